// Round 3
// baseline (43.756 us; speedup 1.0000x reference)
//
#include <hip/hip_runtime.h>
#include <hip/hip_bf16.h>
#include <math.h>

#define HWDIM 512
#define HIDDEN 128
#define N_RAYS 524288
#define NUM_CAMS 4096
#define ALPHA 1e-4f

typedef __attribute__((ext_vector_type(4))) float f32x4;
typedef __attribute__((ext_vector_type(8))) short bf16x8;

__device__ __forceinline__ unsigned short f2bf(float f) {
    union { float f; unsigned u; } v; v.f = f;
    unsigned r = v.u + 0x7FFFu + ((v.u >> 16) & 1u);   // RNE
    return (unsigned short)(r >> 16);
}
__device__ __forceinline__ float bf2f(unsigned short s) {
    union { unsigned u; float f; } v; v.u = ((unsigned)s) << 16;
    return v.f;
}

// ---------------------------------------------------------------------------
// Kernel 1: one thread per (cam, feature, y-row). 4096*96*2 = 786432 threads.
// Each thread: 2 same-line taps of one bilinear row, wy-weighted; partner
// rows combined via shfl_xor(1). Max occupancy (32 waves/CU), 1 distinct
// line-request per thread -> max outstanding-miss concurrency.
// ---------------------------------------------------------------------------
__global__ __launch_bounds__(256) void sample_kernel(
    const float* __restrict__ t,
    const float* __restrict__ pxy,
    const float* __restrict__ pxz,
    const float* __restrict__ pyz,
    unsigned short* __restrict__ codes)
{
    const int g = blockIdx.x * 256 + threadIdx.x;     // 786432 launched exactly
    const int cam = g / 192;
    const int r = g - cam * 192;
    const int f = r >> 1;          // 0..95
    const int ysel = r & 1;
    const int p = f >> 5;
    const int c = f & 31;

    const float ts0 = t[cam * 3 + 0];
    const float ts1 = t[cam * 3 + 1];
    const float ts2 = t[cam * 3 + 2];

    const float* plane;
    float cx, cy;
    if (p == 0)      { plane = pxy; cx = ts0; cy = ts1; }
    else if (p == 1) { plane = pxz; cx = ts0; cy = ts2; }
    else             { plane = pyz; cx = ts1; cy = ts2; }

    const float x = (cx + 1.0f) * 0.5f * (float)(HWDIM - 1);
    const float y = (cy + 1.0f) * 0.5f * (float)(HWDIM - 1);
    const float x0f = floorf(x);
    const float y0f = floorf(y);
    const float wx = x - x0f;
    const float wy = y - y0f;
    const int x0 = min(max((int)x0f, 0), HWDIM - 1);
    const int x1 = min(max((int)x0f + 1, 0), HWDIM - 1);
    const int y0 = min(max((int)y0f, 0), HWDIM - 1);
    const int y1 = min(max((int)y0f + 1, 0), HWDIM - 1);

    const int yr = ysel ? y1 : y0;
    const float wyv = ysel ? wy : (1.0f - wy);

    const float* base = plane + (size_t)c * (HWDIM * HWDIM) + yr * HWDIM;
    const float v0 = base[x0];
    const float v1 = base[x1];

    const float row = (v0 * (1.0f - wx) + v1 * wx) * wyv;
    const float other = __shfl_xor(row, 1);
    if (!ysel) codes[cam * 96 + f] = f2bf(row + other);
}

// ---------------------------------------------------------------------------
// Kernel 2: MFMA MLP. 256 blocks x 256 threads; block = 16 cams, 4 waves.
// float4-vectorized weight staging -> LDS bf16 transposed (padded strides).
// ---------------------------------------------------------------------------
#define W1S 104   // 96 + 8 pad (shorts)
#define W2S 136   // 128 + 8 pad
#define HS  136

__global__ __launch_bounds__(256) void mlp_kernel(
    const unsigned short* __restrict__ codes,
    const float* __restrict__ t,
    const float* __restrict__ w1, const float* __restrict__ b1,
    const float* __restrict__ w2, const float* __restrict__ b2,
    const float* __restrict__ w3, const float* __restrict__ b3,
    const float* __restrict__ init_c2w,
    float* __restrict__ table)
{
    const int tid  = threadIdx.x;
    const int lane = tid & 63;
    const int wave = tid >> 6;
    const int cam0 = blockIdx.x * 16;
    const int ncol = lane & 15;
    const int kgrp = lane >> 4;

    __shared__ unsigned short w1t[128][W1S];
    __shared__ unsigned short w2t[128][W2S];
    __shared__ unsigned short h1t[16][HS];
    __shared__ unsigned short h2t[16][HS];
    __shared__ float b1s[128], b2s[128], w3s[384];
    __shared__ float rotc[16][3];
    __shared__ float c2ws[16][12];

    // --- stage weights (float4 global loads, transpose + bf16 into LDS) ---
    {
        const float4* w1v = (const float4*)w1;
        for (int i = tid; i < (96 * 128) / 4; i += 256) {
            const float4 v = w1v[i];
            const int flat = i * 4;
            const int k = flat >> 7, n = flat & 127;
            w1t[n + 0][k] = f2bf(v.x);
            w1t[n + 1][k] = f2bf(v.y);
            w1t[n + 2][k] = f2bf(v.z);
            w1t[n + 3][k] = f2bf(v.w);
        }
        const float4* w2v = (const float4*)w2;
        for (int i = tid; i < (128 * 128) / 4; i += 256) {
            const float4 v = w2v[i];
            const int flat = i * 4;
            const int k = flat >> 7, n = flat & 127;
            w2t[n + 0][k] = f2bf(v.x);
            w2t[n + 1][k] = f2bf(v.y);
            w2t[n + 2][k] = f2bf(v.z);
            w2t[n + 3][k] = f2bf(v.w);
        }
    }
    if (tid < 128) { b1s[tid] = b1[tid]; b2s[tid] = b2[tid]; }
    for (int i = tid; i < 384; i += 256) w3s[i] = w3[i];
    __syncthreads();

    const int nb0 = wave * 32 + ncol;
    const int nb1 = nb0 + 16;

    // --- layer 1: codes(16x96) @ w1 + b1, silu ---
    f32x4 acc0, acc1;
    {
        const float bv0 = b1s[nb0], bv1 = b1s[nb1];
        acc0 = (f32x4){bv0, bv0, bv0, bv0};
        acc1 = (f32x4){bv1, bv1, bv1, bv1};
    }
    const unsigned short* arow = codes + (size_t)(cam0 + ncol) * 96;
    #pragma unroll
    for (int k0 = 0; k0 < 96; k0 += 32) {
        const bf16x8 a   = *reinterpret_cast<const bf16x8*>(arow + k0 + kgrp * 8);
        const bf16x8 bb0 = *reinterpret_cast<const bf16x8*>(&w1t[nb0][k0 + kgrp * 8]);
        const bf16x8 bb1 = *reinterpret_cast<const bf16x8*>(&w1t[nb1][k0 + kgrp * 8]);
        acc0 = __builtin_amdgcn_mfma_f32_16x16x32_bf16(a, bb0, acc0, 0, 0, 0);
        acc1 = __builtin_amdgcn_mfma_f32_16x16x32_bf16(a, bb1, acc1, 0, 0, 0);
    }
    #pragma unroll
    for (int r = 0; r < 4; ++r) {
        const int camr = kgrp * 4 + r;
        const float v0 = acc0[r];
        const float v1 = acc1[r];
        h1t[camr][nb0] = f2bf(v0 / (1.0f + __expf(-v0)));
        h1t[camr][nb1] = f2bf(v1 / (1.0f + __expf(-v1)));
    }
    __syncthreads();

    // --- layer 2: h1(16x128) @ w2 + b2, silu ---
    {
        const float bv0 = b2s[nb0], bv1 = b2s[nb1];
        acc0 = (f32x4){bv0, bv0, bv0, bv0};
        acc1 = (f32x4){bv1, bv1, bv1, bv1};
    }
    #pragma unroll
    for (int k0 = 0; k0 < 128; k0 += 32) {
        const bf16x8 a   = *reinterpret_cast<const bf16x8*>(&h1t[ncol][k0 + kgrp * 8]);
        const bf16x8 bb0 = *reinterpret_cast<const bf16x8*>(&w2t[nb0][k0 + kgrp * 8]);
        const bf16x8 bb1 = *reinterpret_cast<const bf16x8*>(&w2t[nb1][k0 + kgrp * 8]);
        acc0 = __builtin_amdgcn_mfma_f32_16x16x32_bf16(a, bb0, acc0, 0, 0, 0);
        acc1 = __builtin_amdgcn_mfma_f32_16x16x32_bf16(a, bb1, acc1, 0, 0, 0);
    }
    #pragma unroll
    for (int r = 0; r < 4; ++r) {
        const int camr = kgrp * 4 + r;
        const float v0 = acc0[r];
        const float v1 = acc1[r];
        h2t[camr][nb0] = f2bf(v0 / (1.0f + __expf(-v0)));
        h2t[camr][nb1] = f2bf(v1 / (1.0f + __expf(-v1)));
    }
    __syncthreads();

    // --- layer 3: h2(16x128) @ w3(128x3) + b3, * ALPHA ---
    if (tid < 64) {
        const int cam = tid >> 2, c = tid & 3;
        if (c < 3) {
            float acc = b3[c];
            for (int k = 0; k < 128; ++k)
                acc += bf2f(h2t[cam][k]) * w3s[k * 3 + c];
            rotc[cam][c] = acc * ALPHA;
        }
    }
    __syncthreads();

    // --- Rodrigues + [R|ts] ---
    if (tid < 16) {
        const int cam = tid;
        const float a = rotc[cam][0], b = rotc[cam][1], c = rotc[cam][2];
        const float th2 = a * a + b * b + c * c;
        const float th = sqrtf(th2);
        const float A = sinf(th) / (th + 1e-10f);
        const float B = (1.0f - cosf(th)) / (th2 + 1e-10f);
        const float ts0 = t[(cam0 + cam) * 3 + 0];
        const float ts1 = t[(cam0 + cam) * 3 + 1];
        const float ts2 = t[(cam0 + cam) * 3 + 2];
        c2ws[cam][0]  = 1.0f + B * (-(c * c + b * b));
        c2ws[cam][1]  = A * (-c) + B * (a * b);
        c2ws[cam][2]  = A * b + B * (a * c);
        c2ws[cam][3]  = ts0;
        c2ws[cam][4]  = A * c + B * (a * b);
        c2ws[cam][5]  = 1.0f + B * (-(c * c + a * a));
        c2ws[cam][6]  = A * (-a) + B * (b * c);
        c2ws[cam][7]  = ts1;
        c2ws[cam][8]  = A * (-b) + B * (a * c);
        c2ws[cam][9]  = A * a + B * (b * c);
        c2ws[cam][10] = 1.0f + B * (-(a * a + b * b));
        c2ws[cam][11] = ts2;
    }
    __syncthreads();

    // --- out = c2w @ init_c2w[cam]; 16 threads per cam ---
    {
        const int cam = tid >> 4, e = tid & 15, i = e >> 2, j = e & 3;
        const float* ic = init_c2w + (size_t)(cam0 + cam) * 16;
        float v;
        if (i < 3) {
            const float* cw = c2ws[cam];
            v = cw[i * 4 + 0] * ic[0 + j]
              + cw[i * 4 + 1] * ic[4 + j]
              + cw[i * 4 + 2] * ic[8 + j]
              + cw[i * 4 + 3] * ic[12 + j];
        } else {
            v = ic[12 + j];
        }
        table[(size_t)cam0 * 16 + tid] = v;
    }
}

// ---------------------------------------------------------------------------
// Kernel 3: gather per-camera 4x4 into per-ray output (float4 per thread).
// ---------------------------------------------------------------------------
__global__ __launch_bounds__(256) void gather_kernel(
    const int* __restrict__ cam_id,
    const float4* __restrict__ table,
    float4* __restrict__ out)
{
    const int idx = blockIdx.x * blockDim.x + threadIdx.x;
    if (idx >= N_RAYS * 4) return;
    const int ray = idx >> 2;
    const int q = idx & 3;
    const int cid = cam_id[ray];
    out[idx] = table[cid * 4 + q];
}

extern "C" void kernel_launch(void* const* d_in, const int* in_sizes, int n_in,
                              void* d_out, int out_size, void* d_ws, size_t ws_size,
                              hipStream_t stream) {
    const int*   cam_id   = (const int*)  d_in[0];
    const float* t        = (const float*)d_in[1];
    const float* pxy      = (const float*)d_in[2];
    const float* pxz      = (const float*)d_in[3];
    const float* pyz      = (const float*)d_in[4];
    const float* w1       = (const float*)d_in[5];
    const float* b1       = (const float*)d_in[6];
    const float* w2       = (const float*)d_in[7];
    const float* b2       = (const float*)d_in[8];
    const float* w3       = (const float*)d_in[9];
    const float* b3       = (const float*)d_in[10];
    const float* init_c2w = (const float*)d_in[11];

    float* table = (float*)d_ws;                                   // 256 KB
    unsigned short* codes = (unsigned short*)((char*)d_ws + NUM_CAMS * 16 * 4);

    sample_kernel<<<(NUM_CAMS * 192) / 256, 256, 0, stream>>>(t, pxy, pxz, pyz, codes);

    mlp_kernel<<<NUM_CAMS / 16, 256, 0, stream>>>(
        codes, t, w1, b1, w2, b2, w3, b3, init_c2w, table);

    const int total = N_RAYS * 4;
    gather_kernel<<<(total + 255) / 256, 256, 0, stream>>>(
        cam_id, (const float4*)table, (float4*)d_out);
}

// Round 4
// 41.543 us; speedup vs baseline: 1.0533x; 1.0533x over previous
//
#include <hip/hip_runtime.h>
#include <hip/hip_bf16.h>
#include <math.h>

#define HWDIM 512
#define HIDDEN 128
#define N_RAYS 524288
#define NUM_CAMS 4096
#define ALPHA 1e-4f

typedef __attribute__((ext_vector_type(4))) float f32x4;
typedef __attribute__((ext_vector_type(8))) short bf16x8;

__device__ __forceinline__ unsigned short f2bf(float f) {
    union { float f; unsigned u; } v; v.f = f;
    unsigned r = v.u + 0x7FFFu + ((v.u >> 16) & 1u);   // RNE
    return (unsigned short)(r >> 16);
}
__device__ __forceinline__ float bf2f(unsigned short s) {
    union { unsigned u; float f; } v; v.u = ((unsigned)s) << 16;
    return v.f;
}

// ---------------------------------------------------------------------------
// Kernel 1: deep-MLP sample. One thread per (feature, cam-pair):
// 96 features x 2048 pairs = 196608 threads (768 blocks).
// Each thread issues 8 independent scattered loads (2 cams x 4 taps) before
// any FMA -> 4 distinct cache lines in flight per lane (vs 1 in prior round).
// Feature-major indexing: wave lanes share (plane,channel), consecutive cams
// -> coalesced t reads, scattered plane reads (unavoidable).
// ---------------------------------------------------------------------------
__global__ __launch_bounds__(256) void sample_kernel(
    const float* __restrict__ t,
    const float* __restrict__ pxy,
    const float* __restrict__ pxz,
    const float* __restrict__ pyz,
    unsigned short* __restrict__ codes)
{
    const int idx = blockIdx.x * 256 + threadIdx.x;   // exactly 196608
    const int f  = idx >> 11;        // 0..95  (feature)
    const int pr = idx & 2047;       // cam pair
    const int cam0 = pr * 2;
    const int p = f >> 5;
    const int c = f & 31;

    const float* plane = (p == 0) ? pxy : ((p == 1) ? pxz : pyz);
    const float* pc = plane + (size_t)c * (HWDIM * HWDIM);

    const float* ptrs[2][4];
    float wxa[2], wya[2];

    #pragma unroll
    for (int i = 0; i < 2; ++i) {
        const int cam = cam0 + i;
        const float ts0 = t[cam * 3 + 0];
        const float ts1 = t[cam * 3 + 1];
        const float ts2 = t[cam * 3 + 2];
        float cx, cy;
        if (p == 0)      { cx = ts0; cy = ts1; }
        else if (p == 1) { cx = ts0; cy = ts2; }
        else             { cx = ts1; cy = ts2; }

        const float x = (cx + 1.0f) * 0.5f * (float)(HWDIM - 1);
        const float y = (cy + 1.0f) * 0.5f * (float)(HWDIM - 1);
        const float x0f = floorf(x);
        const float y0f = floorf(y);
        wxa[i] = x - x0f;
        wya[i] = y - y0f;
        const int x0 = min(max((int)x0f, 0), HWDIM - 1);
        const int x1 = min(max((int)x0f + 1, 0), HWDIM - 1);
        const int y0 = min(max((int)y0f, 0), HWDIM - 1);
        const int y1 = min(max((int)y0f + 1, 0), HWDIM - 1);

        ptrs[i][0] = pc + y0 * HWDIM + x0;
        ptrs[i][1] = pc + y0 * HWDIM + x1;
        ptrs[i][2] = pc + y1 * HWDIM + x0;
        ptrs[i][3] = pc + y1 * HWDIM + x1;
    }

    // issue all 8 loads back-to-back (independent; one waitcnt at consumption)
    float v[2][4];
    #pragma unroll
    for (int i = 0; i < 2; ++i)
        #pragma unroll
        for (int j = 0; j < 4; ++j)
            v[i][j] = *ptrs[i][j];

    #pragma unroll
    for (int i = 0; i < 2; ++i) {
        const float wx = wxa[i], wy = wya[i];
        const float val = v[i][0] * (1.0f - wx) * (1.0f - wy)
                        + v[i][1] * wx          * (1.0f - wy)
                        + v[i][2] * (1.0f - wx) * wy
                        + v[i][3] * wx          * wy;
        codes[(cam0 + i) * 96 + f] = f2bf(val);
    }
}

// ---------------------------------------------------------------------------
// Kernel 2: MFMA MLP. 256 blocks x 256 threads; block = 16 cams, 4 waves.
// ---------------------------------------------------------------------------
#define W1S 104   // 96 + 8 pad (shorts)
#define W2S 136   // 128 + 8 pad
#define HS  136

__global__ __launch_bounds__(256) void mlp_kernel(
    const unsigned short* __restrict__ codes,
    const float* __restrict__ t,
    const float* __restrict__ w1, const float* __restrict__ b1,
    const float* __restrict__ w2, const float* __restrict__ b2,
    const float* __restrict__ w3, const float* __restrict__ b3,
    const float* __restrict__ init_c2w,
    float* __restrict__ table)
{
    const int tid  = threadIdx.x;
    const int lane = tid & 63;
    const int wave = tid >> 6;
    const int cam0 = blockIdx.x * 16;
    const int ncol = lane & 15;
    const int kgrp = lane >> 4;

    __shared__ unsigned short w1t[128][W1S];
    __shared__ unsigned short w2t[128][W2S];
    __shared__ unsigned short h1t[16][HS];
    __shared__ unsigned short h2t[16][HS];
    __shared__ float b1s[128], b2s[128], w3s[384];
    __shared__ float rotc[16][3];
    __shared__ float c2ws[16][12];

    {
        const float4* w1v = (const float4*)w1;
        for (int i = tid; i < (96 * 128) / 4; i += 256) {
            const float4 v = w1v[i];
            const int flat = i * 4;
            const int k = flat >> 7, n = flat & 127;
            w1t[n + 0][k] = f2bf(v.x);
            w1t[n + 1][k] = f2bf(v.y);
            w1t[n + 2][k] = f2bf(v.z);
            w1t[n + 3][k] = f2bf(v.w);
        }
        const float4* w2v = (const float4*)w2;
        for (int i = tid; i < (128 * 128) / 4; i += 256) {
            const float4 v = w2v[i];
            const int flat = i * 4;
            const int k = flat >> 7, n = flat & 127;
            w2t[n + 0][k] = f2bf(v.x);
            w2t[n + 1][k] = f2bf(v.y);
            w2t[n + 2][k] = f2bf(v.z);
            w2t[n + 3][k] = f2bf(v.w);
        }
    }
    if (tid < 128) { b1s[tid] = b1[tid]; b2s[tid] = b2[tid]; }
    for (int i = tid; i < 384; i += 256) w3s[i] = w3[i];
    __syncthreads();

    const int nb0 = wave * 32 + ncol;
    const int nb1 = nb0 + 16;

    f32x4 acc0, acc1;
    {
        const float bv0 = b1s[nb0], bv1 = b1s[nb1];
        acc0 = (f32x4){bv0, bv0, bv0, bv0};
        acc1 = (f32x4){bv1, bv1, bv1, bv1};
    }
    const unsigned short* arow = codes + (size_t)(cam0 + ncol) * 96;
    #pragma unroll
    for (int k0 = 0; k0 < 96; k0 += 32) {
        const bf16x8 a   = *reinterpret_cast<const bf16x8*>(arow + k0 + kgrp * 8);
        const bf16x8 bb0 = *reinterpret_cast<const bf16x8*>(&w1t[nb0][k0 + kgrp * 8]);
        const bf16x8 bb1 = *reinterpret_cast<const bf16x8*>(&w1t[nb1][k0 + kgrp * 8]);
        acc0 = __builtin_amdgcn_mfma_f32_16x16x32_bf16(a, bb0, acc0, 0, 0, 0);
        acc1 = __builtin_amdgcn_mfma_f32_16x16x32_bf16(a, bb1, acc1, 0, 0, 0);
    }
    #pragma unroll
    for (int r = 0; r < 4; ++r) {
        const int camr = kgrp * 4 + r;
        const float v0 = acc0[r];
        const float v1 = acc1[r];
        h1t[camr][nb0] = f2bf(v0 / (1.0f + __expf(-v0)));
        h1t[camr][nb1] = f2bf(v1 / (1.0f + __expf(-v1)));
    }
    __syncthreads();

    {
        const float bv0 = b2s[nb0], bv1 = b2s[nb1];
        acc0 = (f32x4){bv0, bv0, bv0, bv0};
        acc1 = (f32x4){bv1, bv1, bv1, bv1};
    }
    #pragma unroll
    for (int k0 = 0; k0 < 128; k0 += 32) {
        const bf16x8 a   = *reinterpret_cast<const bf16x8*>(&h1t[ncol][k0 + kgrp * 8]);
        const bf16x8 bb0 = *reinterpret_cast<const bf16x8*>(&w2t[nb0][k0 + kgrp * 8]);
        const bf16x8 bb1 = *reinterpret_cast<const bf16x8*>(&w2t[nb1][k0 + kgrp * 8]);
        acc0 = __builtin_amdgcn_mfma_f32_16x16x32_bf16(a, bb0, acc0, 0, 0, 0);
        acc1 = __builtin_amdgcn_mfma_f32_16x16x32_bf16(a, bb1, acc1, 0, 0, 0);
    }
    #pragma unroll
    for (int r = 0; r < 4; ++r) {
        const int camr = kgrp * 4 + r;
        const float v0 = acc0[r];
        const float v1 = acc1[r];
        h2t[camr][nb0] = f2bf(v0 / (1.0f + __expf(-v0)));
        h2t[camr][nb1] = f2bf(v1 / (1.0f + __expf(-v1)));
    }
    __syncthreads();

    if (tid < 64) {
        const int cam = tid >> 2, c = tid & 3;
        if (c < 3) {
            float acc = b3[c];
            for (int k = 0; k < 128; ++k)
                acc += bf2f(h2t[cam][k]) * w3s[k * 3 + c];
            rotc[cam][c] = acc * ALPHA;
        }
    }
    __syncthreads();

    if (tid < 16) {
        const int cam = tid;
        const float a = rotc[cam][0], b = rotc[cam][1], c = rotc[cam][2];
        const float th2 = a * a + b * b + c * c;
        const float th = sqrtf(th2);
        const float A = sinf(th) / (th + 1e-10f);
        const float B = (1.0f - cosf(th)) / (th2 + 1e-10f);
        const float ts0 = t[(cam0 + cam) * 3 + 0];
        const float ts1 = t[(cam0 + cam) * 3 + 1];
        const float ts2 = t[(cam0 + cam) * 3 + 2];
        c2ws[cam][0]  = 1.0f + B * (-(c * c + b * b));
        c2ws[cam][1]  = A * (-c) + B * (a * b);
        c2ws[cam][2]  = A * b + B * (a * c);
        c2ws[cam][3]  = ts0;
        c2ws[cam][4]  = A * c + B * (a * b);
        c2ws[cam][5]  = 1.0f + B * (-(c * c + a * a));
        c2ws[cam][6]  = A * (-a) + B * (b * c);
        c2ws[cam][7]  = ts1;
        c2ws[cam][8]  = A * (-b) + B * (a * c);
        c2ws[cam][9]  = A * a + B * (b * c);
        c2ws[cam][10] = 1.0f + B * (-(a * a + b * b));
        c2ws[cam][11] = ts2;
    }
    __syncthreads();

    {
        const int cam = tid >> 4, e = tid & 15, i = e >> 2, j = e & 3;
        const float* ic = init_c2w + (size_t)(cam0 + cam) * 16;
        float v;
        if (i < 3) {
            const float* cw = c2ws[cam];
            v = cw[i * 4 + 0] * ic[0 + j]
              + cw[i * 4 + 1] * ic[4 + j]
              + cw[i * 4 + 2] * ic[8 + j]
              + cw[i * 4 + 3] * ic[12 + j];
        } else {
            v = ic[12 + j];
        }
        table[(size_t)cam0 * 16 + tid] = v;
    }
}

// ---------------------------------------------------------------------------
// Kernel 3: gather per-camera 4x4 into per-ray output (float4 per thread).
// ---------------------------------------------------------------------------
__global__ __launch_bounds__(256) void gather_kernel(
    const int* __restrict__ cam_id,
    const float4* __restrict__ table,
    float4* __restrict__ out)
{
    const int idx = blockIdx.x * blockDim.x + threadIdx.x;
    if (idx >= N_RAYS * 4) return;
    const int ray = idx >> 2;
    const int q = idx & 3;
    const int cid = cam_id[ray];
    out[idx] = table[cid * 4 + q];
}

extern "C" void kernel_launch(void* const* d_in, const int* in_sizes, int n_in,
                              void* d_out, int out_size, void* d_ws, size_t ws_size,
                              hipStream_t stream) {
    const int*   cam_id   = (const int*)  d_in[0];
    const float* t        = (const float*)d_in[1];
    const float* pxy      = (const float*)d_in[2];
    const float* pxz      = (const float*)d_in[3];
    const float* pyz      = (const float*)d_in[4];
    const float* w1       = (const float*)d_in[5];
    const float* b1       = (const float*)d_in[6];
    const float* w2       = (const float*)d_in[7];
    const float* b2       = (const float*)d_in[8];
    const float* w3       = (const float*)d_in[9];
    const float* b3       = (const float*)d_in[10];
    const float* init_c2w = (const float*)d_in[11];

    float* table = (float*)d_ws;                                   // 256 KB
    unsigned short* codes = (unsigned short*)((char*)d_ws + NUM_CAMS * 16 * 4);

    sample_kernel<<<(96 * 2048) / 256, 256, 0, stream>>>(t, pxy, pxz, pyz, codes);

    mlp_kernel<<<NUM_CAMS / 16, 256, 0, stream>>>(
        codes, t, w1, b1, w2, b2, w3, b3, init_c2w, table);

    const int total = N_RAYS * 4;
    gather_kernel<<<(total + 255) / 256, 256, 0, stream>>>(
        cam_id, (const float4*)table, (float4*)d_out);
}